// Round 7
// baseline (309.874 us; speedup 1.0000x reference)
//
#include <hip/hip_runtime.h>

// Problem constants (B=4, S=2048 -> T=8192 tokens; H=1024; E=8 experts)
constexpr int kT = 8192;
constexpr int kH = 1024;
constexpr int kE = 8;
constexpr int kMaxTiles = 72;     // kT/128 + kE
constexpr int kCntStride = 32;    // pad expert counters to separate 128B cache lines

typedef short short8 __attribute__((ext_vector_type(8)));
typedef float floatx4 __attribute__((ext_vector_type(4)));

__device__ inline unsigned short f2b(float f) {
    union { float f; unsigned int u; } v; v.f = f;
    unsigned int r = v.u + 0x7FFFu + ((v.u >> 16) & 1u);  // round-to-nearest-even
    return (unsigned short)(r >> 16);
}

#define GLDS16(gp, lp)                                                                  \
    __builtin_amdgcn_global_load_lds(                                                   \
        (const __attribute__((address_space(1))) unsigned int*)(gp),                    \
        (__attribute__((address_space(3))) unsigned int*)(lp), 16, 0, 0)

// ---------------- K1: fused prep ----------------
//   [0,2048)     : transpose expert_w [E][k][n] f32 -> Wt [E][n][k] bf16
//   [2048,6144)  : x f32 -> xb bf16 (2 rows/block) + FULL router fused:
//                  the block already holds 2 x-rows in registers, so the 8 expert
//                  dots cost 64 FMAs/thread against L1-resident rw (32 KB), then
//                  wave-butterfly + LDS reduce -> argmax/softmax/gate/rank/perm2.
//                  fp32 throughout (bf16 logits risk argmax flips). Last router
//                  block builds the m-tile table. cnt/done pre-zeroed by memset.
__global__ __launch_bounds__(256) void k_prep(const float* __restrict__ W,
                                              unsigned short* __restrict__ Wt,
                                              const float* __restrict__ x,
                                              unsigned short* __restrict__ xb,
                                              const float* __restrict__ rw,
                                              const float* __restrict__ rb,
                                              float* __restrict__ gate,
                                              int* __restrict__ perm2,
                                              int* __restrict__ cnt,
                                              int* __restrict__ done,
                                              int* __restrict__ tile_e,
                                              int* __restrict__ tile_row) {
    __shared__ float lds[64][65];   // transpose path scratch
    __shared__ float red[4][8];     // router cross-wave partials
    int bid = blockIdx.x;
    int tid = threadIdx.x;
    if (bid < 2048) {
        // ---- transpose path ----
        int kb = bid & 15, nb = (bid >> 4) & 15, e = bid >> 8;
        int rr = tid >> 4, c4 = tid & 15;
        const float* Wp = W + ((size_t)e << 20) + (size_t)(kb * 64) * kH + nb * 64;
#pragma unroll
        for (int p = 0; p < 4; ++p) {
            int r = p * 16 + rr;  // local k
            float4 v = *(const float4*)(Wp + (size_t)r * kH + c4 * 4);
            lds[r][c4 * 4 + 0] = v.x; lds[r][c4 * 4 + 1] = v.y;
            lds[r][c4 * 4 + 2] = v.z; lds[r][c4 * 4 + 3] = v.w;
        }
        __syncthreads();
        unsigned short* Wo = Wt + ((size_t)e << 20) + (size_t)(nb * 64) * kH + kb * 64;
#pragma unroll
        for (int p = 0; p < 4; ++p) {
            int n = p * 16 + rr;  // local n
            ushort4 o;
            o.x = f2b(lds[c4 * 4 + 0][n]);
            o.y = f2b(lds[c4 * 4 + 1][n]);
            o.z = f2b(lds[c4 * 4 + 2][n]);
            o.w = f2b(lds[c4 * 4 + 3][n]);
            *(ushort4*)(Wo + (size_t)n * kH + c4 * 4) = o;
        }
        return;
    }
    // ---- x->bf16 + router path: 2 rows per block, 8 f32/thread ----
    int rbk = bid - 2048;                       // 0..4095
    int row = tid >> 7;                         // 0..1 (waves 0,1 = row 0; 2,3 = row 1)
    int t = rbk * 2 + row;
    int col = (tid & 127) * 8;
    const float* xp = x + (size_t)t * kH + col;
    float4 v0 = *(const float4*)xp;
    float4 v1 = *(const float4*)(xp + 4);
    ushort4 o0, o1;
    o0.x = f2b(v0.x); o0.y = f2b(v0.y); o0.z = f2b(v0.z); o0.w = f2b(v0.w);
    o1.x = f2b(v1.x); o1.y = f2b(v1.y); o1.z = f2b(v1.z); o1.w = f2b(v1.w);
    unsigned short* op = xb + (size_t)t * kH + col;
    *(ushort4*)op = o0;
    *(ushort4*)(op + 4) = o1;

    // partial logits for all 8 experts (rw is 32 KB -> L1/L2-resident)
    float pe[8];
#pragma unroll
    for (int e2 = 0; e2 < 8; ++e2) pe[e2] = 0.f;
#pragma unroll
    for (int j = 0; j < 8; ++j) {
        float xv = (j < 4) ? (&v0.x)[j] : (&v1.x)[j - 4];
        const float* wr = rw + (size_t)(col + j) * kE;
        float4 w0 = *(const float4*)wr;
        float4 w1 = *(const float4*)(wr + 4);
        pe[0] += xv * w0.x; pe[1] += xv * w0.y; pe[2] += xv * w0.z; pe[3] += xv * w0.w;
        pe[4] += xv * w1.x; pe[5] += xv * w1.y; pe[6] += xv * w1.z; pe[7] += xv * w1.w;
    }
    // wave butterfly (each wave is entirely within one row)
#pragma unroll
    for (int s = 1; s < 64; s <<= 1)
#pragma unroll
        for (int e2 = 0; e2 < 8; ++e2) pe[e2] += __shfl_xor(pe[e2], s);
    int wv = tid >> 6;
    if ((tid & 63) == 0)
#pragma unroll
        for (int e2 = 0; e2 < 8; ++e2) red[wv][e2] = pe[e2];
    __syncthreads();
    // lanes 0..15 of wave 0: (row rr, expert ee)
    if (tid < 16) {
        int rr = tid >> 3, ee = tid & 7;
        float logit = red[rr * 2][ee] + red[rr * 2 + 1][ee] + rb[ee];
        float m = logit; int bi = ee;
#pragma unroll
        for (int s = 1; s < 8; s <<= 1) {       // argmax, first-max tie-break
            float om = __shfl_xor(m, s);
            int   ob = __shfl_xor(bi, s);
            if (om > m || (om == m && ob < bi)) { m = om; bi = ob; }
        }
        float p = __expf(logit - m);
        float sum = p;
#pragma unroll
        for (int s = 1; s < 8; s <<= 1) sum += __shfl_xor(sum, s);
        if (ee == 0) {
            int tt = rbk * 2 + rr;
            gate[tt] = 1.0f / sum;              // softmax prob at argmax
            int rk = atomicAdd(&cnt[bi * kCntStride], 1);
            perm2[bi * kT + rk] = tt;           // sorted row -> token
        }
    }
    // ---- last router block builds the m-tile table (expert-LOCAL rows) ----
    __syncthreads();
    if (tid == 0) {
        __threadfence();
        int old = atomicAdd(done, 1);
        if (old == 4095) {
            __threadfence();
            int tt = 0;
            for (int ee = 0; ee < kE; ++ee) {
                int c = atomicAdd(&cnt[ee * kCntStride], 0);   // device-coherent read
                int nt = (c + 127) >> 7;
                for (int i = 0; i < nt; ++i) { tile_e[tt] = ee; tile_row[tt] = i << 7; ++tt; }
            }
            for (; tt < kMaxTiles; ++tt) tile_e[tt] = -1;
        }
    }
}

// ---------------- K2: grouped GEMM, 128x128 tile, BK=64, mfma_f32_16x16x32_bf16 --------
// A-tiles are gathered ON THE FLY from xb via perm2 (per-lane global addresses into
// global_load_lds; LDS dest stays uniform-base+lane*16). Pad rows (>= cnt[e]) read
// token 0 and are skipped in the epilogue — no zero-fill pass, no gathered A array.
// Staging rows are 128 B (8 x 16B chunks) with chunk-XOR swizzle on the GLOBAL side
// (LDS[r][s] = G[r][s^(r&7)]); fragment reads un-swizzle with sw = (g^(l15&7)).
constexpr int kBK = 64;

__global__ __launch_bounds__(256, 2) void k_gemm(const unsigned short* __restrict__ xb,
                                                 const unsigned short* __restrict__ Wt,
                                                 const float* __restrict__ eb,
                                                 const int* __restrict__ perm2,
                                                 const float* __restrict__ gate,
                                                 const int* __restrict__ cnt,
                                                 const int* __restrict__ tile_e,
                                                 const int* __restrict__ tile_row,
                                                 float* __restrict__ out) {
    int bm = blockIdx.x, bn = blockIdx.y;
    int e = tile_e[bm];
    if (e < 0) return;
    int l0 = tile_row[bm];                       // expert-local row base
    int ce = cnt[e * kCntStride];
    const int* pe = perm2 + e * kT;

    __shared__ __align__(16) unsigned short As[128 * kBK];   // 16 KB
    __shared__ __align__(16) unsigned short Bs[128 * kBK];   // 16 KB

    int tid = threadIdx.x;
    int wave = tid >> 6, lane = tid & 63;
    int wm = wave & 1, wn = wave >> 1;           // 2x2 waves over 128x128
    int quad = lane >> 4, l15 = lane & 15;

    floatx4 acc[4][4];
#pragma unroll
    for (int i = 0; i < 4; ++i)
#pragma unroll
        for (int j = 0; j < 4; ++j) acc[i][j] = floatx4{0.f, 0.f, 0.f, 0.f};

    // staging: wave stages rows [wave*32, wave*32+32), 4 issues of 8 rows each.
    int lrow8 = lane >> 3;                       // 0..7
    int lseg8 = (lane & 7) ^ lrow8;              // swizzled 16B chunk (global side)
    const unsigned short* aPj[4];
#pragma unroll
    for (int j = 0; j < 4; ++j) {
        int lr = l0 + wave * 32 + j * 8 + lrow8;
        int tok = (lr < ce) ? pe[lr] : 0;        // pad rows read token 0, skipped later
        aPj[j] = xb + (size_t)tok * kH + lseg8 * 8;
    }
    const unsigned short* bP = Wt + ((size_t)e << 20)
                             + (size_t)(bn * 128 + wave * 32 + lrow8) * kH + lseg8 * 8;
    unsigned short* lA = &As[(wave * 32) * kBK];
    unsigned short* lB = &Bs[(wave * 32) * kBK];

    // fragment read chunk: global seg g = ks*4+quad at row l15 -> LDS seg g^(l15&7)
    int sw0 = ((0 * 4 + quad) ^ (l15 & 7)) * 8;
    int sw1 = ((1 * 4 + quad) ^ (l15 & 7)) * 8;

    for (int k0 = 0; k0 < kH; k0 += kBK) {
        __syncthreads();                         // prior iter's fragment reads complete
#pragma unroll
        for (int j = 0; j < 4; ++j) {
            GLDS16(aPj[j] + k0, lA + j * 8 * kBK);
            GLDS16(bP + (size_t)(j * 8) * kH + k0, lB + j * 8 * kBK);
        }
        __syncthreads();                         // drains vmcnt -> tile visible

        short8 af[4][2], bf[4][2];
#pragma unroll
        for (int i = 0; i < 4; ++i) {
            int r = (wm * 64 + i * 16 + l15) * kBK;
            af[i][0] = *(const short8*)&As[r + sw0];
            af[i][1] = *(const short8*)&As[r + sw1];
        }
#pragma unroll
        for (int i = 0; i < 4; ++i) {
            int r = (wn * 64 + i * 16 + l15) * kBK;
            bf[i][0] = *(const short8*)&Bs[r + sw0];
            bf[i][1] = *(const short8*)&Bs[r + sw1];
        }
#pragma unroll
        for (int ks = 0; ks < 2; ++ks)
#pragma unroll
            for (int i = 0; i < 4; ++i)
#pragma unroll
                for (int j = 0; j < 4; ++j)
                    acc[i][j] = __builtin_amdgcn_mfma_f32_16x16x32_bf16(af[i][ks], bf[j][ks],
                                                                        acc[i][j], 0, 0, 0);
    }

    // epilogue: C row = quad*4 + reg, col = lane&15 (verified m89/m91 mapping)
    int colbase = bn * 128 + wn * 64;
#pragma unroll
    for (int i = 0; i < 4; ++i) {
        int rl = l0 + wm * 64 + i * 16 + quad * 4;
#pragma unroll
        for (int rg = 0; rg < 4; ++rg) {
            int lr = rl + rg;
            if (lr >= ce) continue;         // pad row
            int tok = pe[lr];
            float g = gate[tok];
            float* op = out + (size_t)tok * kH;
#pragma unroll
            for (int j = 0; j < 4; ++j) {
                int col = colbase + j * 16 + l15;
                op[col] = g * (acc[i][j][rg] + eb[e * kH + col]);
            }
        }
    }
}

extern "C" void kernel_launch(void* const* d_in, const int* in_sizes, int n_in,
                              void* d_out, int out_size, void* d_ws, size_t ws_size,
                              hipStream_t stream) {
    const float* x  = (const float*)d_in[0];   // [T,H]
    const float* rw = (const float*)d_in[1];   // [H,E]
    const float* rb = (const float*)d_in[2];   // [E]
    const float* ew = (const float*)d_in[3];   // [E,H,H]
    const float* eb = (const float*)d_in[4];   // [E,H]
    float* out = (float*)d_out;                // [T,H]

    char* p = (char*)d_ws;
    unsigned short* Wt = (unsigned short*)p; p += (size_t)kE * kH * kH * 2;   // 16 MB
    unsigned short* xb = (unsigned short*)p; p += (size_t)kT * kH * 2;        // 16 MB
    float* gate  = (float*)p; p += (size_t)kT * 4;
    int* perm2   = (int*)p;   p += (size_t)kE * kT * 4;                       // 256 KB
    int* cnt     = (int*)p;   p += kE * kCntStride * 4;   // 128B-padded counters
    int* done    = (int*)p;   p += 64;
    int* tile_e  = (int*)p;   p += kMaxTiles * 4;
    int* tile_r  = (int*)p;   p += kMaxTiles * 4;

    // zero the padded counters + done flag (rank atomics live in k_prep now)
    hipMemsetAsync(cnt, 0, kE * kCntStride * 4 + 64, stream);
    k_prep<<<6144, 256, 0, stream>>>(ew, Wt, x, xb, rw, rb, gate, perm2, cnt, done,
                                     tile_e, tile_r);
    dim3 gg(kMaxTiles, kH / 128);
    k_gemm<<<gg, 256, 0, stream>>>(xb, Wt, eb, perm2, gate, cnt, tile_e, tile_r, out);
}

// Round 8
// 165.552 us; speedup vs baseline: 1.8718x; 1.8718x over previous
//
#include <hip/hip_runtime.h>

// Problem constants (B=4, S=2048 -> T=8192 tokens; H=1024; E=8 experts)
constexpr int kT = 8192;
constexpr int kH = 1024;
constexpr int kE = 8;
constexpr int kMaxTiles = 72;     // kT/128 + kE
constexpr int kCntStride = 32;    // pad expert counters to separate 128B cache lines

typedef short short8 __attribute__((ext_vector_type(8)));
typedef float floatx4 __attribute__((ext_vector_type(4)));

__device__ inline unsigned short f2b(float f) {
    union { float f; unsigned int u; } v; v.f = f;
    unsigned int r = v.u + 0x7FFFu + ((v.u >> 16) & 1u);  // round-to-nearest-even
    return (unsigned short)(r >> 16);
}

#define GLDS16(gp, lp)                                                                  \
    __builtin_amdgcn_global_load_lds(                                                   \
        (const __attribute__((address_space(1))) unsigned int*)(gp),                    \
        (__attribute__((address_space(3))) unsigned int*)(lp), 16, 0, 0)

// ---------------- K1: fused prep (NO global atomics — R7 lesson) ----------------
//   [0,2048)     : transpose expert_w [E][k][n] f32 -> Wt [E][n][k] bf16
//   [2048,6144)  : x f32 -> xb bf16 + router logits for the block's 2 tokens.
//                  Strided lane layout (h = j*64+lane): x/xb fully coalesced and
//                  rw[h][0..7] reads are contiguous 2KB/wave bursts (L1-resident).
//                  Butterfly + 128B LDS reduce -> argmax/softmax; writes ONLY
//                  gate[t], idx[t]. Rank/perm/tile-table live in narrow k_rank.
__global__ __launch_bounds__(256) void k_prep(const float* __restrict__ W,
                                              unsigned short* __restrict__ Wt,
                                              const float* __restrict__ x,
                                              unsigned short* __restrict__ xb,
                                              const float* __restrict__ rw,
                                              const float* __restrict__ rb,
                                              float* __restrict__ gate,
                                              int* __restrict__ idx,
                                              int* __restrict__ cnt,
                                              int* __restrict__ done) {
    __shared__ float lds[64][65];   // transpose path scratch
    __shared__ float red[4][8];     // router cross-wave partials
    int bid = blockIdx.x;
    int tid = threadIdx.x;
    if (bid == 0 && tid < kE + 1) {              // zero padded cnt[] and done flag
        if (tid < kE) cnt[tid * kCntStride] = 0; else *done = 0;
    }
    if (bid < 2048) {
        // ---- transpose path ----
        int kb = bid & 15, nb = (bid >> 4) & 15, e = bid >> 8;
        int rr = tid >> 4, c4 = tid & 15;
        const float* Wp = W + ((size_t)e << 20) + (size_t)(kb * 64) * kH + nb * 64;
#pragma unroll
        for (int p = 0; p < 4; ++p) {
            int r = p * 16 + rr;  // local k
            float4 v = *(const float4*)(Wp + (size_t)r * kH + c4 * 4);
            lds[r][c4 * 4 + 0] = v.x; lds[r][c4 * 4 + 1] = v.y;
            lds[r][c4 * 4 + 2] = v.z; lds[r][c4 * 4 + 3] = v.w;
        }
        __syncthreads();
        unsigned short* Wo = Wt + ((size_t)e << 20) + (size_t)(nb * 64) * kH + kb * 64;
#pragma unroll
        for (int p = 0; p < 4; ++p) {
            int n = p * 16 + rr;  // local n
            ushort4 o;
            o.x = f2b(lds[c4 * 4 + 0][n]);
            o.y = f2b(lds[c4 * 4 + 1][n]);
            o.z = f2b(lds[c4 * 4 + 2][n]);
            o.w = f2b(lds[c4 * 4 + 3][n]);
            *(ushort4*)(Wo + (size_t)n * kH + c4 * 4) = o;
        }
        return;
    }
    // ---- x->bf16 + router path: 2 tokens/block; wave w: row=w>>1, half=w&1 ----
    int rbk = bid - 2048;                       // 0..4095
    int w = tid >> 6, lane = tid & 63;
    int row = w >> 1, half = w & 1;
    int t = rbk * 2 + row;
    const float* xp = x + (size_t)t * kH + half * 512;
    unsigned short* xop = xb + (size_t)t * kH + half * 512;
    float pe[8];
#pragma unroll
    for (int e2 = 0; e2 < 8; ++e2) pe[e2] = 0.f;
#pragma unroll
    for (int j = 0; j < 8; ++j) {
        int h = j * 64 + lane;                  // lane-contiguous: coalesced
        float xv = xp[h];
        xop[h] = f2b(xv);
        const float* wr = rw + (size_t)(half * 512 + h) * kE;
        float4 w0 = *(const float4*)wr;
        float4 w1 = *(const float4*)(wr + 4);
        pe[0] += xv * w0.x; pe[1] += xv * w0.y; pe[2] += xv * w0.z; pe[3] += xv * w0.w;
        pe[4] += xv * w1.x; pe[5] += xv * w1.y; pe[6] += xv * w1.z; pe[7] += xv * w1.w;
    }
    // wave butterfly (wave is entirely within one (row, half))
#pragma unroll
    for (int s = 1; s < 64; s <<= 1)
#pragma unroll
        for (int e2 = 0; e2 < 8; ++e2) pe[e2] += __shfl_xor(pe[e2], s);
    if (lane == 0)
#pragma unroll
        for (int e2 = 0; e2 < 8; ++e2) red[w][e2] = pe[e2];
    __syncthreads();
    // lanes 0..15 of wave 0: (row rr, expert ee)
    if (tid < 16) {
        int rr = tid >> 3, ee = tid & 7;
        float logit = red[rr * 2][ee] + red[rr * 2 + 1][ee] + rb[ee];
        float m = logit; int bi = ee;
#pragma unroll
        for (int s = 1; s < 8; s <<= 1) {       // argmax, first-max tie-break
            float om = __shfl_xor(m, s);
            int   ob = __shfl_xor(bi, s);
            if (om > m || (om == m && ob < bi)) { m = om; bi = ob; }
        }
        float p = __expf(logit - m);
        float sum = p;
#pragma unroll
        for (int s = 1; s < 8; s <<= 1) sum += __shfl_xor(sum, s);
        if (ee == 0) {
            int tt = rbk * 2 + rr;
            gate[tt] = 1.0f / sum;              // softmax prob at argmax
            idx[tt]  = bi;
        }
    }
}

// ---------------- K2: rank/permutation (narrow: 32 blocks — atomics are cheap here) ---
// One token/thread. Block-local LDS histogram -> local rank; ONE global atomic per
// (block, expert) on 128B-padded lines (256 total). Last block builds m-tile table.
__global__ __launch_bounds__(256) void k_rank(const int* __restrict__ idx,
                                              int* __restrict__ perm2,
                                              int* __restrict__ cnt,
                                              int* __restrict__ done,
                                              int* __restrict__ tile_e,
                                              int* __restrict__ tile_row) {
    __shared__ int lcnt[kE];
    __shared__ int lbase[kE];
    int tid = threadIdx.x;
    if (tid < kE) lcnt[tid] = 0;
    __syncthreads();
    int t = blockIdx.x * 256 + tid;
    int bi = idx[t];
    int lrank = atomicAdd(&lcnt[bi], 1);        // LDS atomic: local rank
    __syncthreads();
    if (tid < kE) lbase[tid] = atomicAdd(&cnt[tid * kCntStride], lcnt[tid]);
    __syncthreads();
    perm2[bi * kT + lbase[bi] + lrank] = t;     // sorted row -> token
    __syncthreads();
    if (tid == 0) {
        __threadfence();
        int old = atomicAdd(done, 1);
        if (old == (int)gridDim.x - 1) {
            __threadfence();
            int tt = 0;
            for (int ee = 0; ee < kE; ++ee) {
                int c = atomicAdd(&cnt[ee * kCntStride], 0);   // device-coherent read
                int nt = (c + 127) >> 7;
                for (int i = 0; i < nt; ++i) { tile_e[tt] = ee; tile_row[tt] = i << 7; ++tt; }
            }
            for (; tt < kMaxTiles; ++tt) tile_e[tt] = -1;
        }
    }
}

// ---------------- K3: grouped GEMM, 128x128 tile, BK=64, mfma_f32_16x16x32_bf16 --------
// A-tiles are gathered ON THE FLY from xb via perm2 (per-lane global addresses into
// global_load_lds; LDS dest stays uniform-base+lane*16). Pad rows (>= cnt[e]) read
// token 0 and are skipped in the epilogue — no zero-fill pass, no gathered A array.
// Staging rows are 128 B (8 x 16B chunks) with chunk-XOR swizzle on the GLOBAL side
// (LDS[r][s] = G[r][s^(r&7)]); fragment reads un-swizzle with sw = (g^(l15&7)).
constexpr int kBK = 64;

__global__ __launch_bounds__(256, 2) void k_gemm(const unsigned short* __restrict__ xb,
                                                 const unsigned short* __restrict__ Wt,
                                                 const float* __restrict__ eb,
                                                 const int* __restrict__ perm2,
                                                 const float* __restrict__ gate,
                                                 const int* __restrict__ cnt,
                                                 const int* __restrict__ tile_e,
                                                 const int* __restrict__ tile_row,
                                                 float* __restrict__ out) {
    int bm = blockIdx.x, bn = blockIdx.y;
    int e = tile_e[bm];
    if (e < 0) return;
    int l0 = tile_row[bm];                       // expert-local row base
    int ce = cnt[e * kCntStride];
    const int* pe = perm2 + e * kT;

    __shared__ __align__(16) unsigned short As[128 * kBK];   // 16 KB
    __shared__ __align__(16) unsigned short Bs[128 * kBK];   // 16 KB

    int tid = threadIdx.x;
    int wave = tid >> 6, lane = tid & 63;
    int wm = wave & 1, wn = wave >> 1;           // 2x2 waves over 128x128
    int quad = lane >> 4, l15 = lane & 15;

    floatx4 acc[4][4];
#pragma unroll
    for (int i = 0; i < 4; ++i)
#pragma unroll
        for (int j = 0; j < 4; ++j) acc[i][j] = floatx4{0.f, 0.f, 0.f, 0.f};

    // staging: wave stages rows [wave*32, wave*32+32), 4 issues of 8 rows each.
    int lrow8 = lane >> 3;                       // 0..7
    int lseg8 = (lane & 7) ^ lrow8;              // swizzled 16B chunk (global side)
    const unsigned short* aPj[4];
#pragma unroll
    for (int j = 0; j < 4; ++j) {
        int lr = l0 + wave * 32 + j * 8 + lrow8;
        int tok = (lr < ce) ? pe[lr] : 0;        // pad rows read token 0, skipped later
        aPj[j] = xb + (size_t)tok * kH + lseg8 * 8;
    }
    const unsigned short* bP = Wt + ((size_t)e << 20)
                             + (size_t)(bn * 128 + wave * 32 + lrow8) * kH + lseg8 * 8;
    unsigned short* lA = &As[(wave * 32) * kBK];
    unsigned short* lB = &Bs[(wave * 32) * kBK];

    // fragment read chunk: global seg g = ks*4+quad at row l15 -> LDS seg g^(l15&7)
    int sw0 = ((0 * 4 + quad) ^ (l15 & 7)) * 8;
    int sw1 = ((1 * 4 + quad) ^ (l15 & 7)) * 8;

    for (int k0 = 0; k0 < kH; k0 += kBK) {
        __syncthreads();                         // prior iter's fragment reads complete
#pragma unroll
        for (int j = 0; j < 4; ++j) {
            GLDS16(aPj[j] + k0, lA + j * 8 * kBK);
            GLDS16(bP + (size_t)(j * 8) * kH + k0, lB + j * 8 * kBK);
        }
        __syncthreads();                         // drains vmcnt -> tile visible

        short8 af[4][2], bf[4][2];
#pragma unroll
        for (int i = 0; i < 4; ++i) {
            int r = (wm * 64 + i * 16 + l15) * kBK;
            af[i][0] = *(const short8*)&As[r + sw0];
            af[i][1] = *(const short8*)&As[r + sw1];
        }
#pragma unroll
        for (int i = 0; i < 4; ++i) {
            int r = (wn * 64 + i * 16 + l15) * kBK;
            bf[i][0] = *(const short8*)&Bs[r + sw0];
            bf[i][1] = *(const short8*)&Bs[r + sw1];
        }
#pragma unroll
        for (int ks = 0; ks < 2; ++ks)
#pragma unroll
            for (int i = 0; i < 4; ++i)
#pragma unroll
                for (int j = 0; j < 4; ++j)
                    acc[i][j] = __builtin_amdgcn_mfma_f32_16x16x32_bf16(af[i][ks], bf[j][ks],
                                                                        acc[i][j], 0, 0, 0);
    }

    // epilogue: C row = quad*4 + reg, col = lane&15 (verified m89/m91 mapping)
    int colbase = bn * 128 + wn * 64;
#pragma unroll
    for (int i = 0; i < 4; ++i) {
        int rl = l0 + wm * 64 + i * 16 + quad * 4;
#pragma unroll
        for (int rg = 0; rg < 4; ++rg) {
            int lr = rl + rg;
            if (lr >= ce) continue;         // pad row
            int tok = pe[lr];
            float g = gate[tok];
            float* op = out + (size_t)tok * kH;
#pragma unroll
            for (int j = 0; j < 4; ++j) {
                int col = colbase + j * 16 + l15;
                op[col] = g * (acc[i][j][rg] + eb[e * kH + col]);
            }
        }
    }
}

extern "C" void kernel_launch(void* const* d_in, const int* in_sizes, int n_in,
                              void* d_out, int out_size, void* d_ws, size_t ws_size,
                              hipStream_t stream) {
    const float* x  = (const float*)d_in[0];   // [T,H]
    const float* rw = (const float*)d_in[1];   // [H,E]
    const float* rb = (const float*)d_in[2];   // [E]
    const float* ew = (const float*)d_in[3];   // [E,H,H]
    const float* eb = (const float*)d_in[4];   // [E,H]
    float* out = (float*)d_out;                // [T,H]

    char* p = (char*)d_ws;
    unsigned short* Wt = (unsigned short*)p; p += (size_t)kE * kH * kH * 2;   // 16 MB
    unsigned short* xb = (unsigned short*)p; p += (size_t)kT * kH * 2;        // 16 MB
    float* gate  = (float*)p; p += (size_t)kT * 4;
    int* idx     = (int*)p;   p += (size_t)kT * 4;
    int* perm2   = (int*)p;   p += (size_t)kE * kT * 4;                       // 256 KB
    int* cnt     = (int*)p;   p += kE * kCntStride * 4;   // 128B-padded counters
    int* done    = (int*)p;   p += 64;
    int* tile_e  = (int*)p;   p += kMaxTiles * 4;
    int* tile_r  = (int*)p;   p += kMaxTiles * 4;

    k_prep<<<6144, 256, 0, stream>>>(ew, Wt, x, xb, rw, rb, gate, idx, cnt, done);
    k_rank<<<kT / 256, 256, 0, stream>>>(idx, perm2, cnt, done, tile_e, tile_r);
    dim3 gg(kMaxTiles, kH / 128);
    k_gemm<<<gg, 256, 0, stream>>>(xb, Wt, eb, perm2, gate, cnt, tile_e, tile_r, out);
}